// Round 7
// baseline (1760.793 us; speedup 1.0000x reference)
//
#include <hip/hip_runtime.h>
#include <hip/hip_bf16.h>

// Fused Linear + CrossEntropy on MI355X.
// Round 9: B-operand direct global->VGPR; A stays through LDS.
// Post-mortem R0-R8: MfmaUtil x dur ~= 505 us*% invariant across SEVEN
// schedule variants (incl. SGB-forced interleave, independent blocks) --
// per-body time == T_LDS + T_MFMA summed; instruction order cannot buy
// overlap here. So shrink T_LDS: W fragments are loaded straight from L2
// into registers (per-lane 16B contiguous = clean dwordx4), removing B's
// LDS writes AND reads: per-CU body 3080 -> 1800 LDS cyc, model 5563 ->
// ~4280 cyc. B regs: named ping-pong buffers (no runtime indexing),
// prefetched one full body ahead, drained by the per-body vmcnt(0).
// Cost: W read 2x from L2 (~14 TB/s total, vs 34.5 ceiling); HBM unchanged.

typedef __attribute__((ext_vector_type(8))) short short8;
typedef __attribute__((ext_vector_type(8))) unsigned short ushort8;
typedef __attribute__((ext_vector_type(4))) float f32x4;

#define BT_TOTAL 8192
#define HDIM     2048
#define VDIM     32000
#define IGNORE_INDEX (-100)

constexpr int BM = 256, BN = 256, BK = 64;
constexpr int NVT = VDIM / BN;      // 125 vocab tiles
constexpr int NMT = BT_TOTAL / BM;  // 32 token tiles
constexpr int NKT = HDIM / BK;      // 32 K-tiles

__device__ __forceinline__ unsigned short f2bf(float f) {
    unsigned u = __float_as_uint(f);
    u = (u + 0x7FFFu + ((u >> 16) & 1u)) >> 16;   // RNE
    return (unsigned short)u;
}

__global__ void cvt_kernel(const float* __restrict__ in, unsigned short* __restrict__ out) {
    size_t i = ((size_t)blockIdx.x * blockDim.x + threadIdx.x) * 8;
    float4 a = *reinterpret_cast<const float4*>(in + i);
    float4 b = *reinterpret_cast<const float4*>(in + i + 4);
    ushort8 r;
    r[0] = f2bf(a.x); r[1] = f2bf(a.y); r[2] = f2bf(a.z); r[3] = f2bf(a.w);
    r[4] = f2bf(b.x); r[5] = f2bf(b.y); r[6] = f2bf(b.z); r[7] = f2bf(b.w);
    *reinterpret_cast<ushort8*>(out + i) = r;
}

#define GLDS(gp, lp) __builtin_amdgcn_global_load_lds( \
    (const __attribute__((address_space(1))) void*)(gp), \
    (__attribute__((address_space(3))) void*)(lp), 16, 0, 0)

__global__ __launch_bounds__(512, 2)
void flce_gemm(const unsigned short* __restrict__ xb,
               const unsigned short* __restrict__ wb,
               const int* __restrict__ labels,
               float* __restrict__ pmax, float* __restrict__ psum,
               float* __restrict__ tgt) {
    // LDS (73728 B): A dbuf [buf][kk] 4 x 16KB at 0, scomb 8KB at 65536.
    // A half-tile layout (swizzled, 0-conflict): row r, k-chunk c (8 bf16=16B)
    // at byte (r>>1)*128 + (r&1)*64 + ((c ^ ((r>>1)&3))<<4).
    __shared__ __align__(16) char smem[73728];

    const int t    = threadIdx.x;           // 0..511
    const int lane = t & 63;
    const int wid  = t >> 6;                // 8 waves
    const int li   = lane & 15;
    const int lg   = lane >> 4;             // k-chunk 0..3 within 32-k half
    const int wm   = wid >> 2;              // 2 wave-rows   (128 rows each)
    const int wn   = wid & 3;               // 4 wave-cols   (64 cols each)

    // XCD-bijective supertiled mapping: 4000 blocks, 500/XCD.
    int bid = blockIdx.x;
    int xcd = bid & 7;
    int idx = bid >> 3;                     // 0..499
    int p   = idx / 250;
    int r_  = idx % 250;
    int vt  = r_ >> 1;
    int mt  = xcd * 4 + p * 2 + (r_ & 1);
    const int row0 = mt * BM;
    const int col0 = vt * BN;

    // ---- A staging lane constants (inverse-swizzled global source, linear LDS dest)
    const int rowLane  = 2 * (t >> 3) + ((t >> 2) & 1);     // 0..127 (issue adds +128)
    const int srcChunk = (t & 3) ^ ((t >> 3) & 3);
    const unsigned short* aG = xb + (size_t)(row0 + rowLane) * HDIM + srcChunk * 8;
    char* ldsA = smem;

    // ---- B direct-global lane base: lane (li,lg) of wave (wn) reads
    // W[col0 + wn*64 + nr*16 + li][kt*64 + kk*32 + lg*8 .. +8)  (16B, aligned)
    const unsigned short* bGr = wb + (size_t)(col0 + wn * 64 + li) * HDIM + lg * 8;

    // ---- A fragment-read lane constant
    const int laneFragOff = (li >> 1) * 128 + (li & 1) * 64
                          + ((lg ^ ((li >> 1) & 3)) << 4);

    f32x4 acc[8][4] = {};   // [mr][nr]: rows wm*128+mr*16+lg*4+j, cols wn*64+nr*16+li

    auto stageA = [&](int buf, int kk, int tile) {
        char* d = ldsA + (buf * 2 + kk) * 16384 + wid * 1024;
        const unsigned short* s = aG + tile * 64 + kk * 32;
        GLDS(s, d);
        GLDS(s + (size_t)128 * HDIM, d + 8192);
    };

    short8 bA[4][2], bB[4][2];   // named ping-pong B buffers [nr][kk]

    // ---- prologue: stage A tile 0 -> buf 0; load B tile 0 -> bA
    stageA(0, 0, 0); stageA(0, 1, 0);
    #pragma unroll
    for (int nr = 0; nr < 4; ++nr)
        #pragma unroll
        for (int kk = 0; kk < 2; ++kk)
            bA[nr][kk] = *(const short8*)(bGr + nr * 16 * HDIM + kk * 32);

    // Body KT: vmcnt(0) drains own A-stages + B-loads issued last body
    // (~4300 cyc ago -> ~0 stall); barrier converges (everyone's A[cur]
    // writes visible). Then issue A-stage(kt+1) + B-load(kt+1), then
    // 16 ds_read_b128 (A frags) + 64 MFMA with B from registers.
#define BODY(KT, BU, BL) do {                                                  \
    asm volatile("s_waitcnt vmcnt(0)" ::: "memory");                           \
    __builtin_amdgcn_s_barrier();                                              \
    {                                                                          \
        const int ktn_ = ((KT) + 1 < NKT) ? (KT) + 1 : (KT);                   \
        stageA(((KT) + 1) & 1, 0, ktn_);                                       \
        stageA(((KT) + 1) & 1, 1, ktn_);                                       \
        _Pragma("unroll")                                                      \
        for (int nr = 0; nr < 4; ++nr)                                         \
            _Pragma("unroll")                                                  \
            for (int kk = 0; kk < 2; ++kk)                                     \
                BL[nr][kk] = *(const short8*)(bGr + (size_t)ktn_ * 64          \
                                              + nr * 16 * HDIM + kk * 32);     \
    }                                                                          \
    {                                                                          \
        const char* A0_ = ldsA + (((KT) & 1) * 2 + 0) * 16384 + wm * 8192;     \
        const char* A1_ = ldsA + (((KT) & 1) * 2 + 1) * 16384 + wm * 8192;     \
        short8 a_[4];                                                          \
        _Pragma("unroll")                                                      \
        for (int i = 0; i < 4; ++i) a_[i] = *(const short8*)(A0_ + i * 1024 + laneFragOff); \
        _Pragma("unroll")                                                      \
        for (int mr = 0; mr < 4; ++mr)                                         \
            _Pragma("unroll")                                                  \
            for (int nr = 0; nr < 4; ++nr)                                     \
                acc[mr][nr] = __builtin_amdgcn_mfma_f32_16x16x32_bf16(         \
                    a_[mr], BU[nr][0], acc[mr][nr], 0, 0, 0);                  \
        _Pragma("unroll")                                                      \
        for (int i = 0; i < 4; ++i) a_[i] = *(const short8*)(A0_ + (4 + i) * 1024 + laneFragOff); \
        _Pragma("unroll")                                                      \
        for (int mr = 0; mr < 4; ++mr)                                         \
            _Pragma("unroll")                                                  \
            for (int nr = 0; nr < 4; ++nr)                                     \
                acc[4 + mr][nr] = __builtin_amdgcn_mfma_f32_16x16x32_bf16(     \
                    a_[mr], BU[nr][0], acc[4 + mr][nr], 0, 0, 0);              \
        _Pragma("unroll")                                                      \
        for (int i = 0; i < 4; ++i) a_[i] = *(const short8*)(A1_ + i * 1024 + laneFragOff); \
        _Pragma("unroll")                                                      \
        for (int mr = 0; mr < 4; ++mr)                                         \
            _Pragma("unroll")                                                  \
            for (int nr = 0; nr < 4; ++nr)                                     \
                acc[mr][nr] = __builtin_amdgcn_mfma_f32_16x16x32_bf16(         \
                    a_[mr], BU[nr][1], acc[mr][nr], 0, 0, 0);                  \
        _Pragma("unroll")                                                      \
        for (int i = 0; i < 4; ++i) a_[i] = *(const short8*)(A1_ + (4 + i) * 1024 + laneFragOff); \
        _Pragma("unroll")                                                      \
        for (int mr = 0; mr < 4; ++mr)                                         \
            _Pragma("unroll")                                                  \
            for (int nr = 0; nr < 4; ++nr)                                     \
                acc[4 + mr][nr] = __builtin_amdgcn_mfma_f32_16x16x32_bf16(     \
                    a_[mr], BU[nr][1], acc[4 + mr][nr], 0, 0, 0);              \
    }                                                                          \
} while (0)

    for (int kt = 0; kt < NKT; kt += 2) {
        BODY(kt,     bA, bB);
        BODY(kt + 1, bB, bA);
    }
#undef BODY

    // ---- fused online-softmax epilogue over this 256x256 logits tile ----
    float* scombM = (float*)(smem + 65536);           // [4][256]
    float* scombS = scombM + 1024;                    // [4][256]
    __syncthreads();   // drains dangling prefetches + converges before scomb use

    #pragma unroll
    for (int mr = 0; mr < 8; ++mr) {
        #pragma unroll
        for (int j = 0; j < 4; ++j) {
            float v = fmaxf(fmaxf(acc[mr][0][j], acc[mr][1][j]),
                            fmaxf(acc[mr][2][j], acc[mr][3][j]));
            v = fmaxf(v, __shfl_xor(v, 1));
            v = fmaxf(v, __shfl_xor(v, 2));
            v = fmaxf(v, __shfl_xor(v, 4));
            v = fmaxf(v, __shfl_xor(v, 8));
            float s = __expf(acc[mr][0][j] - v) + __expf(acc[mr][1][j] - v)
                    + __expf(acc[mr][2][j] - v) + __expf(acc[mr][3][j] - v);
            s += __shfl_xor(s, 1);
            s += __shfl_xor(s, 2);
            s += __shfl_xor(s, 4);
            s += __shfl_xor(s, 8);
            int row = wm * 128 + mr * 16 + lg * 4 + j;
            if (li == 0) {
                scombM[wn * 256 + row] = v;
                scombS[wn * 256 + row] = s;
            }
            // target-logit extraction
            int token = row0 + row;
            int lc = labels[token] - col0 - wn * 64;
            if (lc >= 0 && lc < 64 && (lc & 15) == li) {
                int nr = lc >> 4;
                float val = (nr == 0) ? acc[mr][0][j] : (nr == 1) ? acc[mr][1][j]
                          : (nr == 2) ? acc[mr][2][j] : acc[mr][3][j];
                tgt[token] = val;
            }
        }
    }
    __syncthreads();
    if (t < 256) {
        float m = scombM[t], s = scombS[t];
        #pragma unroll
        for (int w = 1; w < 4; ++w) {
            float m2 = scombM[w * 256 + t], s2 = scombS[w * 256 + t];
            float mm = fmaxf(m, m2);
            s = s * __expf(m - mm) + s2 * __expf(m2 - mm);
            m = mm;
        }
        size_t o = (size_t)vt * BT_TOTAL + row0 + t;
        pmax[o] = m;
        psum[o] = s;
    }
}

__global__ void flce_reduce(const float* __restrict__ pmax, const float* __restrict__ psum,
                            const float* __restrict__ tgt, const int* __restrict__ labels,
                            float* __restrict__ accum) {
    int token = blockIdx.x * 256 + threadIdx.x;
    float m = -INFINITY, s = 0.f;
    for (int v = 0; v < NVT; ++v) {
        float pm = pmax[(size_t)v * BT_TOTAL + token];
        float ps = psum[(size_t)v * BT_TOTAL + token];
        float nm = fmaxf(m, pm);
        s = s * __expf(m - nm) + ps * __expf(pm - nm);
        m = nm;
    }
    float nll = 0.f, cnt = 0.f;
    int lab = labels[token];
    if (lab != IGNORE_INDEX) {
        nll = (m + __logf(s)) - tgt[token];
        cnt = 1.f;
    }
    #pragma unroll
    for (int d = 32; d > 0; d >>= 1) {
        nll += __shfl_down(nll, d);
        cnt += __shfl_down(cnt, d);
    }
    __shared__ float sn[4], sc[4];
    int w = threadIdx.x >> 6;
    if ((threadIdx.x & 63) == 0) { sn[w] = nll; sc[w] = cnt; }
    __syncthreads();
    if (threadIdx.x == 0) {
        atomicAdd(&accum[0], sn[0] + sn[1] + sn[2] + sn[3]);
        atomicAdd(&accum[1], sc[0] + sc[1] + sc[2] + sc[3]);
    }
}

__global__ void flce_final(const float* __restrict__ accum, float* __restrict__ out) {
    if (threadIdx.x == 0) out[0] = accum[0] / fmaxf(accum[1], 1.0f);
}

extern "C" void kernel_launch(void* const* d_in, const int* in_sizes, int n_in,
                              void* d_out, int out_size, void* d_ws, size_t ws_size,
                              hipStream_t stream) {
    const float* hs     = (const float*)d_in[0];   // [8192, 2048] fp32
    const int*   labels = (const int*)d_in[1];     // [8192]
    const float* wt     = (const float*)d_in[2];   // [32000, 2048] fp32

    char* ws = (char*)d_ws;
    unsigned short* xb    = (unsigned short*)(ws);                 // 33,554,432 B
    unsigned short* wb    = (unsigned short*)(ws + 33554432);      // 131,072,000 B
    float*          pmax  = (float*)(ws + 164626432);              // 4,096,000 B
    float*          psum  = (float*)(ws + 168722432);              // 4,096,000 B
    float*          tgt   = (float*)(ws + 172818432);              // 32,768 B
    float*          accum = (float*)(ws + 172851200);              // 8 B

    hipMemsetAsync(accum, 0, 8, stream);
    cvt_kernel<<<16777216 / 2048, 256, 0, stream>>>(hs, xb);
    cvt_kernel<<<65536000 / 2048, 256, 0, stream>>>(wt, wb);
    flce_gemm<<<NMT * NVT, 512, 0, stream>>>(xb, wb, labels, pmax, psum, tgt);
    flce_reduce<<<BT_TOTAL / 256, 256, 0, stream>>>(pmax, psum, tgt, labels, accum);
    flce_final<<<1, 64, 0, stream>>>(accum, (float*)d_out);
}

// Round 8
// 1448.066 us; speedup vs baseline: 1.2160x; 1.2160x over previous
//
#include <hip/hip_runtime.h>
#include <hip/hip_bf16.h>

// Fused Linear + CrossEntropy on MI355X.
// Round 10: R0's exact 4-phase skeleton (best measured: 1113 us) with the
// MFMA shape swapped 16x16x32 -> 32x32x16. Rationale: 8 schedule variants
// all obey MfmaUtil x dur ~= 511 us*% (pipes serialize; LDS traffic is
// geometry-fixed). The only mechanism-backed lever left: 32x32x16 runs at
// 2382 vs 2075 TF (m06/m119) = -15% MFMA-pipe cycles for identical math,
// and halves hot-loop MFMA instruction count. Wave tile stays 128x64
// (4 m-frags x 2 n-frags of 32x32), ds_read count/bytes identical, same
// swizzle (<=2-way aliasing per 16-lane group = free). Epilogue remapped to
// the verified 32x32 C/D layout: col=lane&31, row=(reg&3)+8*(reg>>2)+4*hi.

typedef __attribute__((ext_vector_type(8))) short short8;
typedef __attribute__((ext_vector_type(8))) unsigned short ushort8;
typedef __attribute__((ext_vector_type(16))) float f32x16;

#define BT_TOTAL 8192
#define HDIM     2048
#define VDIM     32000
#define IGNORE_INDEX (-100)

constexpr int BM = 256, BN = 256, BK = 64;
constexpr int NVT = VDIM / BN;      // 125 vocab tiles
constexpr int NMT = BT_TOTAL / BM;  // 32 token tiles
constexpr int NKT = HDIM / BK;      // 32 K-tiles

__device__ __forceinline__ unsigned short f2bf(float f) {
    unsigned u = __float_as_uint(f);
    u = (u + 0x7FFFu + ((u >> 16) & 1u)) >> 16;   // RNE
    return (unsigned short)u;
}

__global__ void cvt_kernel(const float* __restrict__ in, unsigned short* __restrict__ out) {
    size_t i = ((size_t)blockIdx.x * blockDim.x + threadIdx.x) * 8;
    float4 a = *reinterpret_cast<const float4*>(in + i);
    float4 b = *reinterpret_cast<const float4*>(in + i + 4);
    ushort8 r;
    r[0] = f2bf(a.x); r[1] = f2bf(a.y); r[2] = f2bf(a.z); r[3] = f2bf(a.w);
    r[4] = f2bf(b.x); r[5] = f2bf(b.y); r[6] = f2bf(b.z); r[7] = f2bf(b.w);
    *reinterpret_cast<ushort8*>(out + i) = r;
}

#define GLDS(gp, lp) __builtin_amdgcn_global_load_lds( \
    (const __attribute__((address_space(1))) void*)(gp), \
    (__attribute__((address_space(3))) void*)(lp), 16, 0, 0)

__global__ __launch_bounds__(512, 2)
void flce_gemm(const unsigned short* __restrict__ xb,
               const unsigned short* __restrict__ wb,
               const int* __restrict__ labels,
               float* __restrict__ pmax, float* __restrict__ psum,
               float* __restrict__ tgt) {
    // LDS: A halves [buf][kk] 4 x 16KB at 0, B halves at 65536, scomb at 131072.
    // Half-tile layout (swizzled): row r, k-chunk c (8 bf16 = 16B) stored at byte
    //   (r>>1)*128 + (r&1)*64 + ((c ^ ((r>>1)&3))<<4)
    __shared__ __align__(16) char smem[139264];

    const int t    = threadIdx.x;           // 0..511
    const int lane = t & 63;
    const int wid  = t >> 6;                // 8 waves
    const int rl   = lane & 31;             // row-in-frag (32x32)
    const int hi   = lane >> 5;             // k-chunk half
    const int wm   = wid >> 2;              // 2 wave-rows   (128 rows each)
    const int wn   = wid & 3;               // 4 wave-cols   (64 cols each)

    // XCD-bijective supertiled mapping: 4000 blocks, 500/XCD.
    int bid = blockIdx.x;
    int xcd = bid & 7;
    int idx = bid >> 3;                     // 0..499
    int p   = idx / 250;
    int r_  = idx % 250;
    int vt  = r_ >> 1;
    int mt  = xcd * 4 + p * 2 + (r_ & 1);
    const int row0 = mt * BM;
    const int col0 = vt * BN;

    // ---- staging lane constants (inverse-swizzled global source, linear LDS dest)
    const int rowLane  = 2 * (t >> 3) + ((t >> 2) & 1);     // 0..127 (issue adds +128)
    const int srcChunk = (t & 3) ^ ((t >> 3) & 3);
    const unsigned short* aG = xb + (size_t)(row0 + rowLane) * HDIM + srcChunk * 8;
    const unsigned short* bG = wb + (size_t)(col0 + rowLane) * HDIM + srcChunk * 8;
    char* ldsA = smem;
    char* ldsB = smem + 65536;

    // ---- 32x32x16 fragment-read lane constant: lane reads operand row rl,
    // k-chunk (2*ks + hi) of a 32-row frag. With the swizzle:
    //   off(ks) = (rl>>1)*128 + (rl&1)*64 + (((2*ks+hi) ^ ((rl>>1)&3))<<4)
    //           = laneOff32 ^ (ks<<5)     since (2+hi)^x = (hi^x)^2.
    const int laneOff32 = (rl >> 1) * 128 + (rl & 1) * 64
                        + ((hi ^ ((rl >> 1) & 3)) << 4);

    f32x16 acc[4][2] = {};  // [mf][nf]: rows wm*128+mf*32+(reg&3)+8*(reg>>2)+4*hi,
                            //           cols wn*64+nf*32+(lane&31)

    auto stageA = [&](int buf, int kk, int tile) {
        char* d = ldsA + (buf * 2 + kk) * 16384 + wid * 1024;
        const unsigned short* s = aG + tile * 64 + kk * 32;
        GLDS(s, d);
        GLDS(s + (size_t)128 * HDIM, d + 8192);
    };
    auto stageB = [&](int buf, int kk, int tile) {
        char* d = ldsB + (buf * 2 + kk) * 16384 + wid * 1024;
        const unsigned short* s = bG + tile * 64 + kk * 32;
        GLDS(s, d);
        GLDS(s + (size_t)128 * HDIM, d + 8192);
    };

    // prologue: tile 0 -> buf 0 (8 loads/wave in flight)
    stageA(0, 0, 0); stageB(0, 0, 0); stageA(0, 1, 0); stageB(0, 1, 0);

    for (int kt = 0; kt < NKT; ++kt) {
        const int cur = kt & 1, nxt = cur ^ 1;
        const int ktn = (kt + 1 < NKT) ? kt + 1 : kt;   // clamped dummy prefetch on last tile
        const char* A0 = ldsA + (cur * 2 + 0) * 16384 + wm * 8192;
        const char* A1 = ldsA + (cur * 2 + 1) * 16384 + wm * 8192;
        const char* B0 = ldsB + (cur * 2 + 0) * 16384 + wn * 4096;
        const char* B1 = ldsB + (cur * 2 + 1) * 16384 + wn * 4096;

        short8 a[2][2], b[2][2];   // [frag-pair][ks]

        // ---- phase 0: kk0, m-frags 0,1 + B
        asm volatile("s_waitcnt vmcnt(4)" ::: "memory");
        __builtin_amdgcn_s_barrier();
        asm volatile("" ::: "memory");
        stageA(nxt, 0, ktn);
        #pragma unroll
        for (int i = 0; i < 2; ++i)
            #pragma unroll
            for (int ks = 0; ks < 2; ++ks) {
                a[i][ks] = *(const short8*)(A0 + i * 2048 + (laneOff32 ^ (ks << 5)));
                b[i][ks] = *(const short8*)(B0 + i * 2048 + (laneOff32 ^ (ks << 5)));
            }
        __builtin_amdgcn_s_setprio(1);
        #pragma unroll
        for (int ks = 0; ks < 2; ++ks)
            #pragma unroll
            for (int mp = 0; mp < 2; ++mp)
                #pragma unroll
                for (int nf = 0; nf < 2; ++nf)
                    acc[mp][nf] = __builtin_amdgcn_mfma_f32_32x32x16_bf16(
                        a[mp][ks], b[nf][ks], acc[mp][nf], 0, 0, 0);
        __builtin_amdgcn_s_setprio(0);

        // ---- phase 1: kk0, m-frags 2,3 (reuse b)
        asm volatile("" ::: "memory");
        __builtin_amdgcn_s_barrier();
        asm volatile("" ::: "memory");
        stageB(nxt, 0, ktn);
        #pragma unroll
        for (int i = 0; i < 2; ++i)
            #pragma unroll
            for (int ks = 0; ks < 2; ++ks)
                a[i][ks] = *(const short8*)(A0 + (2 + i) * 2048 + (laneOff32 ^ (ks << 5)));
        __builtin_amdgcn_s_setprio(1);
        #pragma unroll
        for (int ks = 0; ks < 2; ++ks)
            #pragma unroll
            for (int mp = 0; mp < 2; ++mp)
                #pragma unroll
                for (int nf = 0; nf < 2; ++nf)
                    acc[2 + mp][nf] = __builtin_amdgcn_mfma_f32_32x32x16_bf16(
                        a[mp][ks], b[nf][ks], acc[2 + mp][nf], 0, 0, 0);
        __builtin_amdgcn_s_setprio(0);

        // ---- phase 2: kk1, m-frags 0,1 + B
        asm volatile("s_waitcnt vmcnt(4)" ::: "memory");
        __builtin_amdgcn_s_barrier();
        asm volatile("" ::: "memory");
        stageA(nxt, 1, ktn);
        #pragma unroll
        for (int i = 0; i < 2; ++i)
            #pragma unroll
            for (int ks = 0; ks < 2; ++ks) {
                a[i][ks] = *(const short8*)(A1 + i * 2048 + (laneOff32 ^ (ks << 5)));
                b[i][ks] = *(const short8*)(B1 + i * 2048 + (laneOff32 ^ (ks << 5)));
            }
        __builtin_amdgcn_s_setprio(1);
        #pragma unroll
        for (int ks = 0; ks < 2; ++ks)
            #pragma unroll
            for (int mp = 0; mp < 2; ++mp)
                #pragma unroll
                for (int nf = 0; nf < 2; ++nf)
                    acc[mp][nf] = __builtin_amdgcn_mfma_f32_32x32x16_bf16(
                        a[mp][ks], b[nf][ks], acc[mp][nf], 0, 0, 0);
        __builtin_amdgcn_s_setprio(0);

        // ---- phase 3: kk1, m-frags 2,3 (reuse b)
        asm volatile("" ::: "memory");
        __builtin_amdgcn_s_barrier();
        asm volatile("" ::: "memory");
        stageB(nxt, 1, ktn);
        #pragma unroll
        for (int i = 0; i < 2; ++i)
            #pragma unroll
            for (int ks = 0; ks < 2; ++ks)
                a[i][ks] = *(const short8*)(A1 + (2 + i) * 2048 + (laneOff32 ^ (ks << 5)));
        __builtin_amdgcn_s_setprio(1);
        #pragma unroll
        for (int ks = 0; ks < 2; ++ks)
            #pragma unroll
            for (int mp = 0; mp < 2; ++mp)
                #pragma unroll
                for (int nf = 0; nf < 2; ++nf)
                    acc[2 + mp][nf] = __builtin_amdgcn_mfma_f32_32x32x16_bf16(
                        a[mp][ks], b[nf][ks], acc[2 + mp][nf], 0, 0, 0);
        __builtin_amdgcn_s_setprio(0);
    }

    // ---- fused online-softmax epilogue over this 256x256 logits tile ----
    // 32x32 C/D layout: col = lane&31, row = (reg&3) + 8*(reg>>2) + 4*hi.
    // A full C-row (64 cols) = 2 nf frags x the 32 lanes of half hi.
    float* scombM = (float*)(smem + 131072);          // [4][256]
    float* scombS = scombM + 1024;                    // [4][256]
    __syncthreads();   // drain + converge before scomb use

    #pragma unroll
    for (int mf = 0; mf < 4; ++mf) {
        #pragma unroll
        for (int reg = 0; reg < 16; ++reg) {
            float v = fmaxf(acc[mf][0][reg], acc[mf][1][reg]);
            v = fmaxf(v, __shfl_xor(v, 1));
            v = fmaxf(v, __shfl_xor(v, 2));
            v = fmaxf(v, __shfl_xor(v, 4));
            v = fmaxf(v, __shfl_xor(v, 8));
            v = fmaxf(v, __shfl_xor(v, 16));
            float s = __expf(acc[mf][0][reg] - v) + __expf(acc[mf][1][reg] - v);
            s += __shfl_xor(s, 1);
            s += __shfl_xor(s, 2);
            s += __shfl_xor(s, 4);
            s += __shfl_xor(s, 8);
            s += __shfl_xor(s, 16);
            int row = wm * 128 + mf * 32 + (reg & 3) + ((reg >> 2) << 3) + (hi << 2);
            if (rl == 0) {
                scombM[wn * 256 + row] = v;
                scombS[wn * 256 + row] = s;
            }
            // target-logit extraction
            int token = row0 + row;
            int lc = labels[token] - col0 - wn * 64;
            if (lc >= 0 && lc < 64 && (lc & 31) == rl) {
                float val = (lc >> 5) == 0 ? acc[mf][0][reg] : acc[mf][1][reg];
                tgt[token] = val;
            }
        }
    }
    __syncthreads();
    if (t < 256) {
        float m = scombM[t], s = scombS[t];
        #pragma unroll
        for (int w = 1; w < 4; ++w) {
            float m2 = scombM[w * 256 + t], s2 = scombS[w * 256 + t];
            float mm = fmaxf(m, m2);
            s = s * __expf(m - mm) + s2 * __expf(m2 - mm);
            m = mm;
        }
        size_t o = (size_t)vt * BT_TOTAL + row0 + t;
        pmax[o] = m;
        psum[o] = s;
    }
}

__global__ void flce_reduce(const float* __restrict__ pmax, const float* __restrict__ psum,
                            const float* __restrict__ tgt, const int* __restrict__ labels,
                            float* __restrict__ accum) {
    int token = blockIdx.x * 256 + threadIdx.x;
    float m = -INFINITY, s = 0.f;
    for (int v = 0; v < NVT; ++v) {
        float pm = pmax[(size_t)v * BT_TOTAL + token];
        float ps = psum[(size_t)v * BT_TOTAL + token];
        float nm = fmaxf(m, pm);
        s = s * __expf(m - nm) + ps * __expf(pm - nm);
        m = nm;
    }
    float nll = 0.f, cnt = 0.f;
    int lab = labels[token];
    if (lab != IGNORE_INDEX) {
        nll = (m + __logf(s)) - tgt[token];
        cnt = 1.f;
    }
    #pragma unroll
    for (int d = 32; d > 0; d >>= 1) {
        nll += __shfl_down(nll, d);
        cnt += __shfl_down(cnt, d);
    }
    __shared__ float sn[4], sc[4];
    int w = threadIdx.x >> 6;
    if ((threadIdx.x & 63) == 0) { sn[w] = nll; sc[w] = cnt; }
    __syncthreads();
    if (threadIdx.x == 0) {
        atomicAdd(&accum[0], sn[0] + sn[1] + sn[2] + sn[3]);
        atomicAdd(&accum[1], sc[0] + sc[1] + sc[2] + sc[3]);
    }
}

__global__ void flce_final(const float* __restrict__ accum, float* __restrict__ out) {
    if (threadIdx.x == 0) out[0] = accum[0] / fmaxf(accum[1], 1.0f);
}

extern "C" void kernel_launch(void* const* d_in, const int* in_sizes, int n_in,
                              void* d_out, int out_size, void* d_ws, size_t ws_size,
                              hipStream_t stream) {
    const float* hs     = (const float*)d_in[0];   // [8192, 2048] fp32
    const int*   labels = (const int*)d_in[1];     // [8192]
    const float* wt     = (const float*)d_in[2];   // [32000, 2048] fp32

    char* ws = (char*)d_ws;
    unsigned short* xb    = (unsigned short*)(ws);                 // 33,554,432 B
    unsigned short* wb    = (unsigned short*)(ws + 33554432);      // 131,072,000 B
    float*          pmax  = (float*)(ws + 164626432);              // 4,096,000 B
    float*          psum  = (float*)(ws + 168722432);              // 4,096,000 B
    float*          tgt   = (float*)(ws + 172818432);              // 32,768 B
    float*          accum = (float*)(ws + 172851200);              // 8 B

    hipMemsetAsync(accum, 0, 8, stream);
    cvt_kernel<<<16777216 / 2048, 256, 0, stream>>>(hs, xb);
    cvt_kernel<<<65536000 / 2048, 256, 0, stream>>>(wt, wb);
    flce_gemm<<<NMT * NVT, 512, 0, stream>>>(xb, wb, labels, pmax, psum, tgt);
    flce_reduce<<<BT_TOTAL / 256, 256, 0, stream>>>(pmax, psum, tgt, labels, accum);
    flce_final<<<1, 64, 0, stream>>>(accum, (float*)d_out);
}